// Round 1
// baseline (3887.387 us; speedup 1.0000x reference)
//
#include <hip/hip_runtime.h>
#include <math.h>

#define Hdim 384
#define Wdim 384
#define HW (Hdim * Wdim)          // 147456
#define Bn 8
#define NBLK (HW / 256)           // 576 blocks per image
#define MAXITER 50
#define TOLF 1e-6f
#define EPSF 1e-12f

// ---------- helpers ----------

__device__ __forceinline__ int symidx(int t, int n) {
    // numpy 'symmetric' pad index map (single reflection is enough: pad=2 << n)
    if (t < 0) t = -t - 1;
    else if (t >= n) t = 2 * n - 1 - t;
    return t;
}

__device__ __forceinline__ float blockReduceSum(float v) {
    __shared__ float sm[256];
    sm[threadIdx.x] = v;
    __syncthreads();
    for (int s = 128; s > 0; s >>= 1) {
        if (threadIdx.x < s) sm[threadIdx.x] += sm[threadIdx.x + s];
        __syncthreads();
    }
    float r = sm[0];
    __syncthreads();
    return r;
}

// sym_conv: out[i,j] = sum_{u,v} k[u,v] * g[sym(i+2-u), sym(j+2-v)]
__device__ float symconv(const float* __restrict__ g, const float* kr, int i, int j) {
    float acc = 0.f;
#pragma unroll
    for (int u = 0; u < 5; ++u) {
        int rr = symidx(i + 2 - u, Hdim);
        const float* row = g + rr * Wdim;
#pragma unroll
        for (int v = 0; v < 5; ++v) {
            int cc = symidx(j + 2 - v, Wdim);
            acc += kr[u * 5 + v] * row[cc];
        }
    }
    return acc;
}

// sym_conv_T (adjoint incl. symmetric-pad adjoint):
// out[m,n] = sum_{p in A(m), q in A(n)} sum_{u,v} k[u,v] * ghat[p+u-4, q+v-4]
// A(m) = {m+2} u {1-m if m<2} u {2H+1-m if m>=H-2}; ghat zero outside [0,H)x[0,W)
__device__ float symconvT(const float* __restrict__ g, const float* kr, int m, int n) {
    int pr[2]; int nr = 0;
    pr[nr++] = m + 2;
    if (m < 2)         pr[nr++] = 1 - m;
    if (m >= Hdim - 2) pr[nr++] = 2 * Hdim + 1 - m;
    int pc[2]; int nc = 0;
    pc[nc++] = n + 2;
    if (n < 2)         pc[nc++] = 1 - n;
    if (n >= Wdim - 2) pc[nc++] = 2 * Wdim + 1 - n;

    float acc = 0.f;
    for (int a = 0; a < nr; ++a) {
        int p = pr[a];
        for (int bb = 0; bb < nc; ++bb) {
            int q = pc[bb];
#pragma unroll
            for (int u = 0; u < 5; ++u) {
                int rr = p + u - 4;
                if ((unsigned)rr < (unsigned)Hdim) {
                    const float* row = g + rr * Wdim;
#pragma unroll
                    for (int v = 0; v < 5; ++v) {
                        int cc = q + v - 4;
                        if ((unsigned)cc < (unsigned)Wdim) {
                            acc += kr[u * 5 + v] * row[cc];
                        }
                    }
                }
            }
        }
    }
    return acc;
}

// ---------- kernels ----------

// rdenom = 1 / max(sum_c |f_c|, EPS)
__global__ __launch_bounds__(256) void k_rdenom(const float* __restrict__ f, float* __restrict__ rden) {
    int b = blockIdx.y;
    int p = blockIdx.x * 256 + threadIdx.x;
    const float* fb = f + (size_t)b * 9 * HW + p;
    float s = 0.f;
#pragma unroll
    for (int c = 0; c < 9; ++c) s += fabsf(fb[(size_t)c * HW]);
    s = fmaxf(s, EPSF);
    rden[(size_t)b * HW + p] = 1.0f / s;
}

// b = K^T y ; r = d = b ; x = 0 ; partial sums of b*b
__global__ __launch_bounds__(256) void k_init(const float* __restrict__ y, const float* __restrict__ kk,
                                              float* __restrict__ r, float* __restrict__ d,
                                              float* __restrict__ x, float* __restrict__ part) {
    int b = blockIdx.y;
    int p = blockIdx.x * 256 + threadIdx.x;
    int m = p / Wdim, n = p % Wdim;
    float kr[25];
#pragma unroll
    for (int t = 0; t < 25; ++t) kr[t] = kk[b * 25 + t];
    float v = symconvT(y + (size_t)b * HW, kr, m, n);
    size_t off = (size_t)b * HW + p;
    r[off] = v; d[off] = v; x[off] = 0.f;
    float ps = blockReduceSum(v * v);
    if (threadIdx.x == 0) part[b * NBLK + blockIdx.x] = ps;
}

// delta0, threshold, conv0
__global__ __launch_bounds__(256) void k_reduce_init(const float* __restrict__ part, float* __restrict__ delta,
                                                     float* __restrict__ thr, int* __restrict__ conv) {
    int b = blockIdx.x;
    float s = 0.f;
    for (int i = threadIdx.x; i < NBLK; i += 256) s += part[b * NBLK + i];
    s = blockReduceSum(s);
    if (threadIdx.x == 0) {
        delta[b] = s;
        thr[b] = TOLF * s;
        conv[b] = (s <= TOLF * s) ? 1 : 0;
    }
}

// t1 = sym_conv(d) ; t2 = spatial_conv(d)  (zero pad, kern = f * rdenom at center)
__global__ __launch_bounds__(256) void k_fwd(const float* __restrict__ dvec, const float* __restrict__ f,
                                             const float* __restrict__ rden, const float* __restrict__ kk,
                                             float* __restrict__ t1, float* __restrict__ t2) {
    int b = blockIdx.y;
    int p = blockIdx.x * 256 + threadIdx.x;
    int i = p / Wdim, j = p % Wdim;
    const float* db = dvec + (size_t)b * HW;
    float kr[25];
#pragma unroll
    for (int t = 0; t < 25; ++t) kr[t] = kk[b * 25 + t];
    size_t off = (size_t)b * HW + p;
    t1[off] = symconv(db, kr, i, j);
    float s = 0.f;
#pragma unroll
    for (int c = 0; c < 9; ++c) {
        int rr = i + c / 3 - 1, cc = j + c % 3 - 1;
        if ((unsigned)rr < (unsigned)Hdim && (unsigned)cc < (unsigned)Wdim)
            s += db[rr * Wdim + cc] * f[((size_t)b * 9 + c) * HW + p];
    }
    t2[off] = s * rden[off];
}

// q = sym_conv_T(t1) + lam * spatial_conv_T(t2) ; partial sums of d*q
__global__ __launch_bounds__(256) void k_applyT(const float* __restrict__ t1, const float* __restrict__ t2,
                                                const float* __restrict__ f, const float* __restrict__ rden,
                                                const float* __restrict__ kk, const float* __restrict__ rw,
                                                const float* __restrict__ dvec,
                                                float* __restrict__ q, float* __restrict__ part) {
    int b = blockIdx.y;
    int p = blockIdx.x * 256 + threadIdx.x;
    int m = p / Wdim, n = p % Wdim;
    float kr[25];
#pragma unroll
    for (int t = 0; t < 25; ++t) kr[t] = kk[b * 25 + t];
    size_t bHW = (size_t)b * HW;
    float qv = symconvT(t1 + bHW, kr, m, n);
    float lam = expf(rw[0]);
    float s = 0.f;
#pragma unroll
    for (int c = 0; c < 9; ++c) {
        int rr = m + 1 - c / 3, cc = n + 1 - c % 3;
        if ((unsigned)rr < (unsigned)Hdim && (unsigned)cc < (unsigned)Wdim) {
            size_t pp = (size_t)rr * Wdim + cc;
            s += f[((size_t)b * 9 + c) * HW + pp] * t2[bHW + pp] * rden[bHW + pp];
        }
    }
    qv += lam * s;
    q[bHW + p] = qv;
    float ps = blockReduceSum(dvec[bHW + p] * qv);
    if (threadIdx.x == 0) part[b * NBLK + blockIdx.x] = ps;
}

// conv |= (delta <= thr) ; alpha = conv ? 0 : delta / dot(d,q)
__global__ __launch_bounds__(256) void k_alpha(const float* __restrict__ part, const float* __restrict__ delta,
                                               const float* __restrict__ thr, int* __restrict__ conv,
                                               float* __restrict__ alpha) {
    int b = blockIdx.x;
    float s = 0.f;
    for (int i = threadIdx.x; i < NBLK; i += 256) s += part[b * NBLK + i];
    s = blockReduceSum(s);
    if (threadIdx.x == 0) {
        int cv = conv[b];
        if (delta[b] <= thr[b]) cv = 1;
        conv[b] = cv;
        alpha[b] = cv ? 0.f : delta[b] / s;
    }
}

// x += alpha d ; r -= alpha q ; partial sums of r*r
__global__ __launch_bounds__(256) void k_xr(const float* __restrict__ alpha, const float* __restrict__ dvec,
                                            const float* __restrict__ q, float* __restrict__ x,
                                            float* __restrict__ r, float* __restrict__ part) {
    int b = blockIdx.y;
    size_t off = (size_t)b * HW + blockIdx.x * 256 + threadIdx.x;
    float a = alpha[b];
    float xv = x[off] + a * dvec[off];
    x[off] = xv;
    float rv = r[off] - a * q[off];
    r[off] = rv;
    float ps = blockReduceSum(rv * rv);
    if (threadIdx.x == 0) part[b * NBLK + blockIdx.x] = ps;
}

// beta = delta_new / delta ; delta = delta_new
__global__ __launch_bounds__(256) void k_beta(const float* __restrict__ part, float* __restrict__ delta,
                                              float* __restrict__ beta) {
    int b = blockIdx.x;
    float s = 0.f;
    for (int i = threadIdx.x; i < NBLK; i += 256) s += part[b * NBLK + i];
    s = blockReduceSum(s);
    if (threadIdx.x == 0) {
        beta[b] = s / delta[b];
        delta[b] = s;
    }
}

// d = r + beta * d
__global__ __launch_bounds__(256) void k_dupd(const float* __restrict__ r, const float* __restrict__ beta,
                                              float* __restrict__ dvec) {
    int b = blockIdx.y;
    size_t off = (size_t)b * HW + blockIdx.x * 256 + threadIdx.x;
    dvec[off] = r[off] + beta[b] * dvec[off];
}

// ---------- launch ----------

extern "C" void kernel_launch(void* const* d_in, const int* in_sizes, int n_in,
                              void* d_out, int out_size, void* d_ws, size_t ws_size,
                              hipStream_t stream) {
    const float* y  = (const float*)d_in[0];   // [8,1,384,384]
    const float* kk = (const float*)d_in[1];   // [8,5,5]
    const float* f  = (const float*)d_in[2];   // [8,9,384,384]
    const float* rw = (const float*)d_in[3];   // [1]

    float* x = (float*)d_out;                  // [8,1,384,384]
    float* ws = (float*)d_ws;
    const size_t N = (size_t)Bn * HW;

    float* rden   = ws;
    float* r      = ws + 1 * N;
    float* dv     = ws + 2 * N;
    float* q      = ws + 3 * N;
    float* t1     = ws + 4 * N;
    float* t2     = ws + 5 * N;
    float* dqpart = ws + 6 * N;                 // Bn*NBLK
    float* dnpart = dqpart + (size_t)Bn * NBLK; // Bn*NBLK
    float* delta  = dnpart + (size_t)Bn * NBLK; // Bn
    float* thr    = delta + Bn;                 // Bn
    float* alpha  = thr + Bn;                   // Bn
    float* beta   = alpha + Bn;                 // Bn
    int*   conv   = (int*)(beta + Bn);          // Bn

    dim3 gridP(NBLK, Bn), blk(256);
    dim3 gridS(Bn);

    k_rdenom<<<gridP, blk, 0, stream>>>(f, rden);
    k_init<<<gridP, blk, 0, stream>>>(y, kk, r, dv, x, dnpart);
    k_reduce_init<<<gridS, blk, 0, stream>>>(dnpart, delta, thr, conv);

    for (int it = 0; it < MAXITER; ++it) {
        k_fwd<<<gridP, blk, 0, stream>>>(dv, f, rden, kk, t1, t2);
        k_applyT<<<gridP, blk, 0, stream>>>(t1, t2, f, rden, kk, rw, dv, q, dqpart);
        k_alpha<<<gridS, blk, 0, stream>>>(dqpart, delta, thr, conv, alpha);
        k_xr<<<gridP, blk, 0, stream>>>(alpha, dv, q, x, r, dnpart);
        k_beta<<<gridS, blk, 0, stream>>>(dnpart, delta, beta);
        k_dupd<<<gridP, blk, 0, stream>>>(r, beta, dv);
    }
}